// Round 5
// baseline (55.270 us; speedup 1.0000x reference)
//
#include <hip/hip_runtime.h>
#include <math.h>

#define G     1000
#define B     32
#define NC    2048
#define NT    2048
#define BN    (B * NT)
#define LOG2E 1.4426950408889634f
#define LN2PI 1.8378770664093453f   // ln(2*pi)

#if __has_builtin(__builtin_amdgcn_exp2f)
#define EXP2F(x) __builtin_amdgcn_exp2f(x)
#else
#define EXP2F(x) exp2f(x)
#endif

// ---------------------------------------------------------------------------
// Kernel A v3 (frozen): grid (16 g-tiles x B), block 512 = 64g x 8n.
// ---------------------------------------------------------------------------
__global__ __launch_bounds__(512) void k_smooth(
    const float* __restrict__ xc, const float* __restrict__ yc,
    const float* __restrict__ ls_x, float* __restrict__ h,
    float* __restrict__ loss_slot) {
  __shared__ float sxy[NC * 2];           // {s*x_n, y_n} interleaved, 16KB
  __shared__ float pm[512], ps[512];
  if (blockIdx.x == 0 && blockIdx.y == 0 && threadIdx.x == 0) *loss_slot = 0.f;

  int tid = threadIdx.x;
  int b = blockIdx.y, tile = blockIdx.x;
  float ls = ls_x[0];
  float s  = sqrtf(0.5f * LOG2E) / ls;    // w = exp2(-(s*t - s*x)^2)

  const float* xb = xc + b * NC;
  const float* yb = yc + b * NC;
  for (int n = tid; n < NC; n += 512) {
    sxy[2 * n]     = s * xb[n];
    sxy[2 * n + 1] = yb[n];
  }
  __syncthreads();

  int gl = tid & 63, q = tid >> 6;        // 64 g-slots x 8 n-slices
  int g  = tile * 64 + gl;
  float tgp = s * (-2.2f + (4.4f / 999.f) * (float)g);

  float s0 = 0.f, s1 = 0.f;
  const float4* p = ((const float4*)sxy) + q * (NC / 16);
  #pragma unroll 4
  for (int i = 0; i < NC / 16; ++i) {
    float4 v = p[i];
    float d0 = tgp - v.x; float w0 = EXP2F(-(d0 * d0));
    float d1 = tgp - v.z; float w1 = EXP2F(-(d1 * d1));
    s0 += w0; s1 = fmaf(w0, v.y, s1);
    s0 += w1; s1 = fmaf(w1, v.w, s1);
  }
  pm[tid] = s0; ps[tid] = s1;
  __syncthreads();

  if (q == 0 && g < G) {
    float d0 = s0, d1 = s1;
    #pragma unroll
    for (int k = 1; k < 8; ++k) { d0 += pm[tid + 64 * k]; d1 += ps[tid + 64 * k]; }
    h[(b * 2 + 0) * G + g] = d0;
    h[(b * 2 + 1) * G + g] = d1 / (d0 + 1e-8f);
  }
}

// ---------------------------------------------------------------------------
// Kernel B v4: TILE=64, grid (16 x B) = 512 blocks (exactly 2/CU).
// Buffer col = logical e + 2, CSTR=100. Stage logical [-2, 98) = global
// [ts-10, ts+90). Layers compute e in [0, 80); final outputs e in [8, 72).
// Garbage-absorption: contamination reaches only e<=5 / e>=74 (verified).
// Weights staged COALESCED from global into padded-stride LDS:
//   wt[oc*WSTR + ic*5 + k], WSTR in {11, 81, 161, 81} -> conflict-free reads.
// ---------------------------------------------------------------------------
#define TILE  64
#define NTILE 16
#define CSTR  100

template <int CIN, int COUT, int POS, int NG, int NSUB, int WSTR>
__device__ __forceinline__ void conv_layer(
    const float* __restrict__ in, float* __restrict__ out,
    const float* __restrict__ wt, const float* __restrict__ bias, int tid) {
  int oc  = tid % COUT;
  int sub = tid / COUT;
  if (sub < NSUB) {
    int e0 = sub * POS;                   // col base (window cols [e0, e0+4*NG))
    float acc[POS];
    float bb = bias[oc];
    #pragma unroll
    for (int p = 0; p < POS; ++p) acc[p] = bb;
    for (int ic = 0; ic < CIN; ++ic) {
      const float* ip = in + ic * CSTR + e0;
      float v[NG * 4];
      #pragma unroll
      for (int r = 0; r < NG; ++r) {
        float4 t4 = *(const float4*)(ip + 4 * r);
        v[4*r] = t4.x; v[4*r+1] = t4.y; v[4*r+2] = t4.z; v[4*r+3] = t4.w;
      }
      float w[5];
      #pragma unroll
      for (int k = 0; k < 5; ++k) w[k] = wt[oc * WSTR + ic * 5 + k];
      #pragma unroll
      for (int p = 0; p < POS; ++p)
        #pragma unroll
        for (int k = 0; k < 5; ++k)
          acc[p] = fmaf(v[p + k], w[k], acc[p]);   // out e=e0+p needs cols [e, e+4]
    }
    float* op = out + oc * CSTR + e0 + 2;          // out col = e + 2
    #pragma unroll
    for (int j = 0; j < POS / 2; ++j) {
      float2 o = make_float2(fmaxf(acc[2*j], 0.f), fmaxf(acc[2*j+1], 0.f));
      *(float2*)(op + 2 * j) = o;
    }
  }
}

__global__ __launch_bounds__(256) void k_conv(
    const float* __restrict__ h,
    const float* __restrict__ W1, const float* __restrict__ Bs1,
    const float* __restrict__ W2, const float* __restrict__ Bs2,
    const float* __restrict__ W3, const float* __restrict__ Bs3,
    const float* __restrict__ W4, const float* __restrict__ Bs4,
    float* __restrict__ yg) {
  __shared__ __align__(16) float bufA[32 * CSTR], bufB[32 * CSTR];
  __shared__ float wt1[176], wt2[2592], wt3[2576], wt4[162];
  __shared__ float sB1[16], sB2[32], sB3[16], sB4[2];

  int tid  = threadIdx.x;
  int tile = blockIdx.x, b = blockIdx.y;
  int ts   = tile * TILE;

  // coalesced weight staging into padded strides
  for (int i = tid; i < 160;  i += 256) wt1[(i / 10)  * 11  + i % 10]  = W1[i];
  for (int i = tid; i < 2560; i += 256) wt2[(i / 80)  * 81  + i % 80]  = W2[i];
  for (int i = tid; i < 2560; i += 256) wt3[(i / 160) * 161 + i % 160] = W3[i];
  for (int i = tid; i < 160;  i += 256) wt4[(i / 80)  * 81  + i % 80]  = W4[i];
  if (tid < 16)       sB1[tid]      = Bs1[tid];
  else if (tid < 48)  sB2[tid - 16] = Bs2[tid - 16];
  else if (tid < 64)  sB3[tid - 48] = Bs3[tid - 48];
  else if (tid < 66)  sB4[tid - 64] = Bs4[tid - 64];

  // stage input: col in [0,100) <-> logical col-2 <-> global ts + col - 10
  for (int i = tid; i < 2 * CSTR; i += 256) {
    int c = i >= CSTR, col = i - c * CSTR;
    int g = ts + col - 10;
    bufA[c * CSTR + col] = (g >= 0 && g < G) ? h[(b * 2 + c) * G + g] : 0.f;
  }
  __syncthreads();

  conv_layer<2, 16, 20, 6, 4, 11>(bufA, bufB, wt1, sB1, tid);   // 64 thr
  __syncthreads();
  conv_layer<16, 32, 20, 6, 4, 81>(bufB, bufA, wt2, sB2, tid);  // 128 thr
  __syncthreads();
  conv_layer<32, 16, 12, 4, 7, 161>(bufA, bufB, wt3, sB3, tid); // 112 thr
  __syncthreads();

  // Layer 4: 32 threads, (oc = tid&1, 4 positions each); softplus on ch1
  if (tid < 32) {
    int oc = tid & 1, sub = tid >> 1;
    int e0 = 8 + 4 * sub;                 // col base; outputs e = e0 + p
    float acc[4];
    float bb = sB4[oc];
    #pragma unroll
    for (int p = 0; p < 4; ++p) acc[p] = bb;
    for (int ic = 0; ic < 16; ++ic) {
      const float* ip = bufB + ic * CSTR + e0;
      float4 a = *(const float4*)(ip);
      float4 c4 = *(const float4*)(ip + 4);
      float v[8] = {a.x, a.y, a.z, a.w, c4.x, c4.y, c4.z, c4.w};
      float w[5];
      #pragma unroll
      for (int k = 0; k < 5; ++k) w[k] = wt4[oc * 81 + ic * 5 + k];
      #pragma unroll
      for (int p = 0; p < 4; ++p)
        #pragma unroll
        for (int k = 0; k < 5; ++k)
          acc[p] = fmaf(v[p + k], w[k], acc[p]);
    }
    #pragma unroll
    for (int p = 0; p < 4; ++p) {
      int gp = ts + 4 * sub + p;          // e - 8
      if (gp < G) {
        if (oc == 0) {
          yg[(b * 2 + 0) * G + gp] = acc[p];
        } else {
          float sp_ = fmaxf(acc[p], 0.f) + log1pf(__expf(-fabsf(acc[p])));
          yg[(b * 2 + 1) * G + gp] = sp_;
        }
      }
    }
  }
}

// ---------------------------------------------------------------------------
// Kernel C v4 (frozen): Gaussian recurrence — no exp in the loop.
// ---------------------------------------------------------------------------
__global__ __launch_bounds__(512) void k_pred(
    const float* __restrict__ xt, const float* __restrict__ yt,
    const float* __restrict__ ls_rho, const float* __restrict__ yg,
    float* __restrict__ out) {
  __shared__ float2 sp[G];                // {y0_g, y1_g}, 8KB
  __shared__ float pm[512], ps[512];
  __shared__ float red[8];

  int tid = threadIdx.x;
  int b = blockIdx.y, tile = blockIdx.x;
  float ls = ls_rho[0];
  float s  = sqrtf(0.5f * LOG2E) / ls;
  float dl = s * (4.4f / 999.f);          // delta

  const float* y0 = yg + (b * 2 + 0) * G;
  const float* y1 = yg + (b * 2 + 1) * G;
  for (int g = tid; g < G; g += 512) sp[g] = make_float2(y0[g], y1[g]);
  __syncthreads();

  int tl = tid & 127, qi = tid >> 7;      // 128 t x 4 slices (250 g each)
  int t  = tile * 128 + tl;
  float u  = s * xt[b * NT + t];
  float a  = u + 2.2f * s - dl * (float)(qi * 250);  // u - v_{g0}
  float W  = EXP2F(64.f - a * a);
  float q  = EXP2F(dl * (a + a) - dl * dl);
  float r  = EXP2F(-2.f * dl * dl);

  float mu = 0.f, sg = 0.f;
  const float2* p = sp + qi * 250;
  #pragma unroll 2
  for (int i = 0; i < 250; ++i) {
    float2 v = p[i];
    mu = fmaf(W, v.x, mu);
    sg = fmaf(W, v.y, sg);
    W *= q;
    q *= r;
  }
  pm[tid] = mu; ps[tid] = sg;
  __syncthreads();

  float lp = 0.f;
  if (qi == 0) {
    #pragma unroll
    for (int k = 1; k < 4; ++k) { mu += pm[tid + 128 * k]; sg += ps[tid + 128 * k]; }
    mu *= 0x1p-64f;                        // undo 2^64 scaling
    sg *= 0x1p-64f;
    out[b * NT + t]      = mu;
    out[BN + b * NT + t] = sg;
    float z = (yt[b * NT + t] - mu) / sg;
    lp = -0.5f * z * z - __logf(sg) - 0.5f * LN2PI;
  }
  #pragma unroll
  for (int m = 32; m; m >>= 1) lp += __shfl_xor(lp, m);
  if ((tid & 63) == 0) red[tid >> 6] = lp;
  __syncthreads();
  if (tid == 0) {
    float tot = 0.f;
    #pragma unroll
    for (int i = 0; i < 8; ++i) tot += red[i];
    atomicAdd(out + 2 * BN, -tot * (1.f / (float)NT));
  }
}

extern "C" void kernel_launch(void* const* d_in, const int* in_sizes, int n_in,
                              void* d_out, int out_size, void* d_ws, size_t ws_size,
                              hipStream_t stream) {
  const float* xc  = (const float*)d_in[0];
  const float* yc  = (const float*)d_in[1];
  const float* xt  = (const float*)d_in[2];
  const float* yt  = (const float*)d_in[3];
  const float* lsx = (const float*)d_in[4];
  const float* lsr = (const float*)d_in[5];
  const float* W1  = (const float*)d_in[6];  const float* b1 = (const float*)d_in[7];
  const float* W2  = (const float*)d_in[8];  const float* b2 = (const float*)d_in[9];
  const float* W3  = (const float*)d_in[10]; const float* b3 = (const float*)d_in[11];
  const float* W4  = (const float*)d_in[12]; const float* b4 = (const float*)d_in[13];

  float* out = (float*)d_out;
  float* h   = (float*)d_ws;        // B*2*G
  float* yg  = h + B * 2 * G;       // B*2*G

  k_smooth<<<dim3(16, B), 512, 0, stream>>>(xc, yc, lsx, h, out + 2 * BN);
  k_conv<<<dim3(NTILE, B), 256, 0, stream>>>(h, W1, b1, W2, b2, W3, b3, W4, b4, yg);
  k_pred<<<dim3(16, B), 512, 0, stream>>>(xt, yt, lsr, yg, out);
}

// Round 6
// 50.670 us; speedup vs baseline: 1.0908x; 1.0908x over previous
//
#include <hip/hip_runtime.h>
#include <math.h>

#define G     1000
#define B     32
#define NC    2048
#define NT    2048
#define BN    (B * NT)
#define LOG2E 1.4426950408889634f
#define LN2PI 1.8378770664093453f   // ln(2*pi)

#if __has_builtin(__builtin_amdgcn_exp2f)
#define EXP2F(x) __builtin_amdgcn_exp2f(x)
#else
#define EXP2F(x) exp2f(x)
#endif

// ---------------------------------------------------------------------------
// Kernel A v3 (frozen): grid (16 g-tiles x B), block 512 = 64g x 8n.
// ---------------------------------------------------------------------------
__global__ __launch_bounds__(512) void k_smooth(
    const float* __restrict__ xc, const float* __restrict__ yc,
    const float* __restrict__ ls_x, float* __restrict__ h,
    float* __restrict__ loss_slot) {
  __shared__ float sxy[NC * 2];           // {s*x_n, y_n} interleaved, 16KB
  __shared__ float pm[512], ps[512];
  if (blockIdx.x == 0 && blockIdx.y == 0 && threadIdx.x == 0) *loss_slot = 0.f;

  int tid = threadIdx.x;
  int b = blockIdx.y, tile = blockIdx.x;
  float ls = ls_x[0];
  float s  = sqrtf(0.5f * LOG2E) / ls;    // w = exp2(-(s*t - s*x)^2)

  const float* xb = xc + b * NC;
  const float* yb = yc + b * NC;
  for (int n = tid; n < NC; n += 512) {
    sxy[2 * n]     = s * xb[n];
    sxy[2 * n + 1] = yb[n];
  }
  __syncthreads();

  int gl = tid & 63, q = tid >> 6;        // 64 g-slots x 8 n-slices
  int g  = tile * 64 + gl;
  float tgp = s * (-2.2f + (4.4f / 999.f) * (float)g);

  float s0 = 0.f, s1 = 0.f;
  const float4* p = ((const float4*)sxy) + q * (NC / 16);
  #pragma unroll 4
  for (int i = 0; i < NC / 16; ++i) {
    float4 v = p[i];
    float d0 = tgp - v.x; float w0 = EXP2F(-(d0 * d0));
    float d1 = tgp - v.z; float w1 = EXP2F(-(d1 * d1));
    s0 += w0; s1 = fmaf(w0, v.y, s1);
    s0 += w1; s1 = fmaf(w1, v.w, s1);
  }
  pm[tid] = s0; ps[tid] = s1;
  __syncthreads();

  if (q == 0 && g < G) {
    float d0 = s0, d1 = s1;
    #pragma unroll
    for (int k = 1; k < 8; ++k) { d0 += pm[tid + 64 * k]; d1 += ps[tid + 64 * k]; }
    h[(b * 2 + 0) * G + g] = d0;
    h[(b * 2 + 1) * G + g] = d1 / (d0 + 1e-8f);
  }
}

// ---------------------------------------------------------------------------
// Kernel B v5: TILE=48, grid (21 x B) = 672 blocks, 39.7KB LDS -> 4 blocks/CU
// (16 waves/CU for latency hiding — v4 showed conv is stall-bound, not
// issue-bound). All-256-thread layer mapping (v3 style), POS=4 f4 windows.
// Buffer: 32ch x CSTR=68; col i = global g - ts + 10; stage [ts-10, ts+58).
// Layers compute i in [2,66). Garbage cols {0,1,66,67} contaminate <=2 more
// cols/layer: L4 true on i in [8,60) superset of needed [10,58). Weights
// staged coalesced into padded natural layout wt[oc*WSTR + ic*5 + k],
// WSTR in {11,81,161,81} (odd -> conflict-free lane-stride reads).
// ---------------------------------------------------------------------------
#define TILE  48
#define NTILE 21   // 21*48 = 1008 >= 1000
#define CSTR  68

template <int CIN, int COUT, int WSTR, int NPASS>
__device__ __forceinline__ void conv_layer5(
    const float* __restrict__ in, float* __restrict__ out,
    const float* __restrict__ wt, const float* __restrict__ bias, int tid) {
  #pragma unroll
  for (int pass = 0; pass < NPASS; ++pass) {
    int idx = tid + pass * 256;           // < COUT*16 by construction
    int oc  = idx % COUT;
    int i0  = (idx / COUT) * 4;           // reads [i0, i0+8), writes [i0+2, i0+6)
    float acc[4];
    float bb = bias[oc];
    #pragma unroll
    for (int p = 0; p < 4; ++p) acc[p] = bb;
    for (int ic = 0; ic < CIN; ++ic) {
      const float* ip = in + ic * CSTR + i0;
      float4 va = *(const float4*)ip;
      float4 vb = *(const float4*)(ip + 4);
      float v[8] = {va.x, va.y, va.z, va.w, vb.x, vb.y, vb.z, vb.w};
      const float* wp = wt + oc * WSTR + ic * 5;
      float w[5];
      #pragma unroll
      for (int k = 0; k < 5; ++k) w[k] = wp[k];
      #pragma unroll
      for (int p = 0; p < 4; ++p)
        #pragma unroll
        for (int k = 0; k < 5; ++k)
          acc[p] = fmaf(v[p + k], w[k], acc[p]);
    }
    float* op = out + oc * CSTR + i0 + 2;
    *(float2*)op       = make_float2(fmaxf(acc[0], 0.f), fmaxf(acc[1], 0.f));
    *(float2*)(op + 2) = make_float2(fmaxf(acc[2], 0.f), fmaxf(acc[3], 0.f));
  }
}

__global__ __launch_bounds__(256, 4) void k_conv(
    const float* __restrict__ h,
    const float* __restrict__ W1, const float* __restrict__ Bs1,
    const float* __restrict__ W2, const float* __restrict__ Bs2,
    const float* __restrict__ W3, const float* __restrict__ Bs3,
    const float* __restrict__ W4, const float* __restrict__ Bs4,
    float* __restrict__ yg) {
  __shared__ __align__(16) float bufA[32 * CSTR], bufB[32 * CSTR];
  __shared__ float wt1[176], wt2[2592], wt3[2576], wt4[162];
  __shared__ float sB1[16], sB2[32], sB3[16], sB4[2];

  int tid  = threadIdx.x;
  int tile = blockIdx.x, b = blockIdx.y;
  int ts   = tile * TILE;

  // coalesced weight staging into padded natural-layout strides
  for (int i = tid; i < 160;  i += 256) wt1[(i / 10)  * 11  + i % 10]  = W1[i];
  for (int i = tid; i < 2560; i += 256) wt2[(i / 80)  * 81  + i % 80]  = W2[i];
  for (int i = tid; i < 2560; i += 256) wt3[(i / 160) * 161 + i % 160] = W3[i];
  for (int i = tid; i < 160;  i += 256) wt4[(i / 80)  * 81  + i % 80]  = W4[i];
  if (tid < 16)       sB1[tid]      = Bs1[tid];
  else if (tid < 48)  sB2[tid - 16] = Bs2[tid - 16];
  else if (tid < 64)  sB3[tid - 48] = Bs3[tid - 48];
  else if (tid < 66)  sB4[tid - 64] = Bs4[tid - 64];

  // stage input: col i in [0,68) <-> global g = ts + i - 10
  for (int i = tid; i < 2 * CSTR; i += 256) {
    int c = i >= CSTR, col = i - c * CSTR;
    int g = ts + col - 10;
    bufA[c * CSTR + col] = (g >= 0 && g < G) ? h[(b * 2 + c) * G + g] : 0.f;
  }
  __syncthreads();

  conv_layer5<2, 16, 11, 1>(bufA, bufB, wt1, sB1, tid);
  __syncthreads();
  conv_layer5<16, 32, 81, 2>(bufB, bufA, wt2, sB2, tid);
  __syncthreads();
  conv_layer5<32, 16, 161, 1>(bufA, bufB, wt3, sB3, tid);
  __syncthreads();

  // Layer 4: 96 threads, thread -> (oc, one output); softplus on ch1
  if (tid < 96) {
    int oc = tid >= 48;
    int j  = tid - oc * 48;               // 0..47
    int i  = 10 + j;                      // reads [8, 59] ⊂ true region [6,62)
    float sacc = sB4[oc];
    #pragma unroll
    for (int ic = 0; ic < 16; ++ic) {
      const float* ip = bufB + ic * CSTR + i - 2;
      #pragma unroll
      for (int k = 0; k < 5; ++k)
        sacc = fmaf(ip[k], wt4[oc * 81 + ic * 5 + k], sacc);
    }
    int gp = ts + j;
    if (gp < G) {
      if (oc == 0) {
        yg[(b * 2 + 0) * G + gp] = sacc;
      } else {
        float sp_ = fmaxf(sacc, 0.f) + log1pf(__expf(-fabsf(sacc)));
        yg[(b * 2 + 1) * G + gp] = sp_;
      }
    }
  }
}

// ---------------------------------------------------------------------------
// Kernel C v4 (frozen): Gaussian recurrence — no exp in the loop.
// ---------------------------------------------------------------------------
__global__ __launch_bounds__(512) void k_pred(
    const float* __restrict__ xt, const float* __restrict__ yt,
    const float* __restrict__ ls_rho, const float* __restrict__ yg,
    float* __restrict__ out) {
  __shared__ float2 sp[G];                // {y0_g, y1_g}, 8KB
  __shared__ float pm[512], ps[512];
  __shared__ float red[8];

  int tid = threadIdx.x;
  int b = blockIdx.y, tile = blockIdx.x;
  float ls = ls_rho[0];
  float s  = sqrtf(0.5f * LOG2E) / ls;
  float dl = s * (4.4f / 999.f);          // delta

  const float* y0 = yg + (b * 2 + 0) * G;
  const float* y1 = yg + (b * 2 + 1) * G;
  for (int g = tid; g < G; g += 512) sp[g] = make_float2(y0[g], y1[g]);
  __syncthreads();

  int tl = tid & 127, qi = tid >> 7;      // 128 t x 4 slices (250 g each)
  int t  = tile * 128 + tl;
  float u  = s * xt[b * NT + t];
  float a  = u + 2.2f * s - dl * (float)(qi * 250);  // u - v_{g0}
  float W  = EXP2F(64.f - a * a);
  float q  = EXP2F(dl * (a + a) - dl * dl);
  float r  = EXP2F(-2.f * dl * dl);

  float mu = 0.f, sg = 0.f;
  const float2* p = sp + qi * 250;
  #pragma unroll 2
  for (int i = 0; i < 250; ++i) {
    float2 v = p[i];
    mu = fmaf(W, v.x, mu);
    sg = fmaf(W, v.y, sg);
    W *= q;
    q *= r;
  }
  pm[tid] = mu; ps[tid] = sg;
  __syncthreads();

  float lp = 0.f;
  if (qi == 0) {
    #pragma unroll
    for (int k = 1; k < 4; ++k) { mu += pm[tid + 128 * k]; sg += ps[tid + 128 * k]; }
    mu *= 0x1p-64f;                        // undo 2^64 scaling
    sg *= 0x1p-64f;
    out[b * NT + t]      = mu;
    out[BN + b * NT + t] = sg;
    float z = (yt[b * NT + t] - mu) / sg;
    lp = -0.5f * z * z - __logf(sg) - 0.5f * LN2PI;
  }
  #pragma unroll
  for (int m = 32; m; m >>= 1) lp += __shfl_xor(lp, m);
  if ((tid & 63) == 0) red[tid >> 6] = lp;
  __syncthreads();
  if (tid == 0) {
    float tot = 0.f;
    #pragma unroll
    for (int i = 0; i < 8; ++i) tot += red[i];
    atomicAdd(out + 2 * BN, -tot * (1.f / (float)NT));
  }
}

extern "C" void kernel_launch(void* const* d_in, const int* in_sizes, int n_in,
                              void* d_out, int out_size, void* d_ws, size_t ws_size,
                              hipStream_t stream) {
  const float* xc  = (const float*)d_in[0];
  const float* yc  = (const float*)d_in[1];
  const float* xt  = (const float*)d_in[2];
  const float* yt  = (const float*)d_in[3];
  const float* lsx = (const float*)d_in[4];
  const float* lsr = (const float*)d_in[5];
  const float* W1  = (const float*)d_in[6];  const float* b1 = (const float*)d_in[7];
  const float* W2  = (const float*)d_in[8];  const float* b2 = (const float*)d_in[9];
  const float* W3  = (const float*)d_in[10]; const float* b3 = (const float*)d_in[11];
  const float* W4  = (const float*)d_in[12]; const float* b4 = (const float*)d_in[13];

  float* out = (float*)d_out;
  float* h   = (float*)d_ws;        // B*2*G
  float* yg  = h + B * 2 * G;       // B*2*G

  k_smooth<<<dim3(16, B), 512, 0, stream>>>(xc, yc, lsx, h, out + 2 * BN);
  k_conv<<<dim3(NTILE, B), 256, 0, stream>>>(h, W1, b1, W2, b2, W3, b3, W4, b4, yg);
  k_pred<<<dim3(16, B), 512, 0, stream>>>(xt, yt, lsr, yg, out);
}